// Round 11
// baseline (228.270 us; speedup 1.0000x reference)
//
#include <hip/hip_runtime.h>

typedef short bf16x8 __attribute__((ext_vector_type(8)));
typedef float f32x4 __attribute__((ext_vector_type(4)));
typedef unsigned short ushort8 __attribute__((ext_vector_type(8)));
typedef unsigned short ushort4v __attribute__((ext_vector_type(4)));

#define BATCH 16
#define DCAT 512
#define CIN 256
#define COUT 256
#define HH 64
#define WW 64
#define HP 66
#define WP 66
#define PLANE (HP * WP * 8)  // shorts per c8-plane
#define AHALO 52224          // 408 entries (6 rows x 68 cols) * 128B
#define BBUF 32768

__device__ __forceinline__ unsigned short f2bf(float f) {
  unsigned int u = __float_as_uint(f);
  unsigned int r = (u + 0x7fffu + ((u >> 16) & 1u)) >> 16;
  return (unsigned short)r;
}

// ---------------- MLP layer: one wave per output element (b,c).
template <int IN_DIM>
__global__ void __launch_bounds__(256) mlp_layer(const float* __restrict__ in,
                                                 const float* __restrict__ w,
                                                 const float* __restrict__ bias,
                                                 float* __restrict__ out) {
  int wid = threadIdx.x >> 6, lane = threadIdx.x & 63;
  int oidx = blockIdx.x * 4 + wid;  // (b<<8)|c
  int b = oidx >> 8, c = oidx & 255;
  const float* wr = w + (size_t)c * IN_DIM;
  const float* ir = in + (size_t)b * IN_DIM;
  float sum = 0.f;
#pragma unroll
  for (int d0 = 0; d0 < IN_DIM; d0 += 256) {
    f32x4 wv = *(const f32x4*)(wr + d0 + lane * 4);
    f32x4 iv = *(const f32x4*)(ir + d0 + lane * 4);
    sum += wv[0] * iv[0] + wv[1] * iv[1] + wv[2] * iv[2] + wv[3] * iv[3];
  }
#pragma unroll
  for (int off = 32; off; off >>= 1) sum += __shfl_xor(sum, off, 64);
  if (lane == 0) {
    float a = sum + bias[c];
    out[oidx] = a >= 0.f ? a : 0.01f * a;
  }
}

// ---------------- consolidated prep (tap-major wt): R0-verbatim.
__global__ void __launch_bounds__(256) prep_all(const float* __restrict__ t1,
                                                const float* __restrict__ w2,
                                                const float* __restrict__ b2,
                                                const float* __restrict__ x,
                                                const float* __restrict__ cw,
                                                unsigned short* __restrict__ xpad,
                                                unsigned short* __restrict__ wt) {
  int blk = blockIdx.x;
  int tid = threadIdx.x;

  if (blk >= 1024) {  // ---- prep_w part
    int idx = (blk - 1024) * 256 + tid;  // 9*256*64 = 147456 threads
    int t = idx / 16384;
    int r = idx - t * 16384;  // o*64 + i4
    int o = r >> 6, i4 = r & 63;
    ushort4v v;
#pragma unroll
    for (int j = 0; j < 4; j++) v[j] = f2bf(cw[(o * 256 + i4 * 4 + j) * 9 + t]);
    *(ushort4v*)(wt + ((size_t)(t * COUT + o)) * CIN + i4 * 4) = v;
    return;
  }

  // ---- prep_x part: blk = (b<<6) | (c8<<1) | h
  int h = blk & 1, c8 = (blk >> 1) & 31, b = blk >> 6;
  int wid = tid >> 6, lane = tid & 63;

  float tv = t1[b * CIN + tid];
  float pj[8];
#pragma unroll
  for (int j = 0; j < 8; j++) pj[j] = w2[(size_t)(c8 * 8 + j) * CIN + tid] * tv;

  const float* xb = x + ((size_t)(b * CIN + c8 * 8)) * (HH * WW);
  int gg0 = h * 512 + tid;
  int gg1 = gg0 + 256;
  int hh0 = (gg0 >> 4) + 1, w00 = (gg0 & 15) * 4 + 1;
  int hh1 = (gg1 >> 4) + 1, w01 = (gg1 & 15) * 4 + 1;
  int base0 = (hh0 - 1) * WW + (w00 - 1);
  int base1 = (hh1 - 1) * WW + (w01 - 1);
  f32x4 v0[8], v1[8];
#pragma unroll
  for (int j = 0; j < 8; j++) v0[j] = *(const f32x4*)(xb + j * (HH * WW) + base0);
#pragma unroll
  for (int j = 0; j < 8; j++) v1[j] = *(const f32x4*)(xb + j * (HH * WW) + base1);

#pragma unroll
  for (int off = 32; off; off >>= 1)
#pragma unroll
    for (int j = 0; j < 8; j++) pj[j] += __shfl_xor(pj[j], off, 64);
  __shared__ float red[4][8];
  __shared__ float sv_sh[8];
  if (lane == 0)
#pragma unroll
    for (int j = 0; j < 8; j++) red[wid][j] = pj[j];
  __syncthreads();
  if (tid < 8) {
    float a = red[0][tid] + red[1][tid] + red[2][tid] + red[3][tid] + b2[c8 * 8 + tid];
    sv_sh[tid] = a >= 0.f ? a : 0.01f * a;
  }
  __syncthreads();
  float sv[8];
#pragma unroll
  for (int j = 0; j < 8; j++) sv[j] = sv_sh[j];

  unsigned short* xp = xpad + ((size_t)(b * 32 + c8)) * PLANE;

  if (tid < 130) {
    int i = h * 130 + tid;
    int bh, bw;
    if (i < 66) { bh = 0; bw = i; }
    else if (i < 132) { bh = 65; bw = i - 66; }
    else if (i < 196) { bh = i - 132 + 1; bw = 0; }
    else { bh = i - 196 + 1; bw = 65; }
    ushort8 z = {0, 0, 0, 0, 0, 0, 0, 0};
    *(ushort8*)(xp + (bh * WP + bw) * 8) = z;
  }

  unsigned short* op0 = xp + (hh0 * WP + w00) * 8;
  unsigned short* op1 = xp + (hh1 * WP + w01) * 8;
#pragma unroll
  for (int t2 = 0; t2 < 4; t2++) {
    ushort8 o;
#pragma unroll
    for (int j = 0; j < 8; j++) o[j] = f2bf(v0[j][t2] * sv[j]);
    *(ushort8*)(op0 + t2 * 8) = o;
  }
#pragma unroll
  for (int t2 = 0; t2 < 4; t2++) {
    ushort8 o;
#pragma unroll
    for (int j = 0; j < 8; j++) o[j] = f2bf(v1[j][t2] * sv[j]);
    *(ushort8*)(op1 + t2 * 8) = o;
  }
}

// ---------------- implicit-GEMM conv R11: R7 tap-reuse + m201 2-phase convoy.
// Per kc2: A halo staged once (52KB). Per tap, TWO phases, each
// {stage(ph0), 12 ds_reads, [vmcnt(4) ph0], s_barrier, lgkm0, setprio,
// 32 MFMA, setprio, s_barrier}. The post-MFMA barrier carries NO waitcnt:
// waves cross right after MFMA *issue* and fill the LDS pipe under the
// draining matrix pipe — that is the overlap mechanism (m201/T3+T4+T5).
// B(t+1) staged entirely in tap-t ph0 -> vmcnt(4) at tap t+1 ph0 drains
// B(t+1) with a full tap of cover; ph1 needs no wait.
__device__ __forceinline__ void gl2lds16(const void* g, void* l) {
  __builtin_amdgcn_global_load_lds((const __attribute__((address_space(1))) void*)g,
                                   (__attribute__((address_space(3))) void*)l, 16, 0, 0);
}

#define WAIT_LGKM0()                                        \
  asm volatile("s_waitcnt lgkmcnt(0)" ::: "memory");        \
  __builtin_amdgcn_sched_barrier(0)

__global__ void __launch_bounds__(512, 1) gemm_conv(const unsigned short* __restrict__ xpad,
                                                    const unsigned short* __restrict__ wt,
                                                    float* __restrict__ out) {
  // LDS: A halo [0, 52224), B buf0 [52224, +32K), B buf1 [84992, +32K)
  __shared__ __align__(16) char lds[AHALO + 2 * BBUF];
  int tid = threadIdx.x;
  int wid = tid >> 6, lane = tid & 63;
  int bid = blockIdx.x;
  // XCD swizzle: 256 blocks, 32 contiguous tiles (=2 images) per XCD.
  int m_t = (bid & 7) * 32 + (bid >> 3);
  int m0 = m_t << 8;                 // first pixel of tile (BM=256 = 4 image rows)
  int b = m0 >> 12;
  int h0 = (m0 >> 6) & 63;           // tile covers image rows h0..h0+3
  int wm = wid & 1, wn = wid >> 1;   // 2x4 wave grid, wave tile 128px x 64o

  f32x4 acc[8][4];
#pragma unroll
  for (int mi = 0; mi < 8; mi++)
#pragma unroll
    for (int ni = 0; ni < 4; ni++) acc[mi][ni] = (f32x4){0.f, 0.f, 0.f, 0.f};

  // ---- A halo stager invariants (R7-verbatim)
  const unsigned short* aSrc[7];
#pragma unroll
  for (int i = 0; i < 7; i++) {
    int c = (i * 8 + wid) * 64 + lane;
    int e = c >> 3, cs = c & 7;
    int gs = cs ^ (e & 7);
    int rh = e / 68, wc = e - rh * 68;
    aSrc[i] = xpad + ((size_t)((b * 32 + gs) * HP + (h0 + rh))) * (WP * 8) + wc * 8;
  }

  // ---- B stager invariants (R7-verbatim addressing)
  int o_l = tid >> 3;
  int csb = tid & 7;
  const unsigned short* bL = wt + o_l * CIN + ((csb ^ (o_l & 7)) * 8);

  // ---- reader invariants
  int qa = lane >> 4;
  int l15 = lane & 15;
  int rB = wn * 64 + l15;
  int offB0 = rB * 128 + ((qa ^ (rB & 7)) * 16);
  int offB1 = rB * 128 + (((qa + 4) ^ (rB & 7)) * 16);

#define STAGE_B4(BUF, BG)                                               \
  do {                                                                  \
    char* dB_ = lds + AHALO + (BUF) * BBUF + wid * 1024;                \
    const unsigned short* bg_ = (BG);                                   \
    _Pragma("unroll")                                                   \
    for (int q = 0; q < 4; q++) gl2lds16(bg_ + q * 64 * CIN, dB_ + q * 8192); \
  } while (0)

#define STAGE_A(KOFS)                                                   \
  do {                                                                  \
    size_t ko_ = (KOFS);                                                \
    _Pragma("unroll")                                                   \
    for (int i = 0; i < 6; i++)                                         \
      gl2lds16(aSrc[i] + ko_, lds + (i * 8 + wid) * 1024);              \
    if (wid < 3) gl2lds16(aSrc[6] + ko_, lds + (48 + wid) * 1024);      \
  } while (0)

  // ---- prologue: A halo kc2=0 + B(tap0) into buf 0
  STAGE_A(0);
  STAGE_B4(0, bL);
  asm volatile("s_waitcnt vmcnt(0)" ::: "memory");
  __builtin_amdgcn_s_barrier();

  int cur = 0;
  for (int kc2 = 0; kc2 < 4; kc2++) {
    for (int kh = 0; kh < 3; kh++) {
      for (int kw = 0; kw < 3; kw++) {
        int tap = kh * 3 + kw;

        // ---- A window offsets for this tap (R7-verbatim swizzle math)
        int eb = (wm * 2 + kh) * 68 + l15 + kw;
        int s0 = eb & 7, s1 = (eb + 4) & 7;
        int a00 = eb * 128 + ((qa ^ s0) * 16);
        int a01 = (eb + 68) * 128 + ((qa ^ s1) * 16);
        int a10 = eb * 128 + (((qa + 4) ^ s0) * 16);
        int a11 = (eb + 68) * 128 + (((qa + 4) ^ s1) * 16);
        const char* Bb = lds + AHALO + cur * BBUF;

        // ================ phase 0 (kb0) ================
        // stage B(t+1) fully (4 loads) — or next kc2's tap-0 B at tap 8
        if (tap < 8) {
          STAGE_B4(cur ^ 1, bL + (size_t)(tap + 1) * (COUT * CIN) + kc2 * 64);
        } else if (kc2 < 3) {
          STAGE_B4(cur ^ 1, bL + (kc2 + 1) * 64);
        }
        {
          bf16x8 av[8], bv[4];
#pragma unroll
          for (int mi = 0; mi < 4; mi++) {
            av[mi] = *(const bf16x8*)(lds + a00 + mi * 2048);
            av[4 + mi] = *(const bf16x8*)(lds + a01 + mi * 2048);
          }
#pragma unroll
          for (int ni = 0; ni < 4; ni++)
            bv[ni] = *(const bf16x8*)(Bb + offB0 + ni * 2048);
          // drain B(t): outstanding = {B(t):4 (prev tap), B(t+1):4 (just issued)}
          asm volatile("s_waitcnt vmcnt(4)" ::: "memory");
          __builtin_amdgcn_s_barrier();
          WAIT_LGKM0();
          __builtin_amdgcn_s_setprio(1);
#pragma unroll
          for (int mi = 0; mi < 8; mi++)
#pragma unroll
            for (int ni = 0; ni < 4; ni++)
              acc[mi][ni] = __builtin_amdgcn_mfma_f32_16x16x32_bf16(av[mi], bv[ni],
                                                                    acc[mi][ni], 0, 0, 0);
          __builtin_amdgcn_s_setprio(0);
          __builtin_amdgcn_s_barrier();  // no waitcnt: cross while matrix pipe drains
        }

        // ================ phase 1 (kb1) ================
        {
          bf16x8 aw[8], bw[4];
#pragma unroll
          for (int mi = 0; mi < 4; mi++) {
            aw[mi] = *(const bf16x8*)(lds + a10 + mi * 2048);
            aw[4 + mi] = *(const bf16x8*)(lds + a11 + mi * 2048);
          }
#pragma unroll
          for (int ni = 0; ni < 4; ni++)
            bw[ni] = *(const bf16x8*)(Bb + offB1 + ni * 2048);
          __builtin_amdgcn_s_barrier();
          WAIT_LGKM0();
          __builtin_amdgcn_s_setprio(1);
#pragma unroll
          for (int mi = 0; mi < 8; mi++)
#pragma unroll
            for (int ni = 0; ni < 4; ni++)
              acc[mi][ni] = __builtin_amdgcn_mfma_f32_16x16x32_bf16(aw[mi], bw[ni],
                                                                    acc[mi][ni], 0, 0, 0);
          __builtin_amdgcn_s_setprio(0);
          __builtin_amdgcn_s_barrier();
        }

        cur ^= 1;
      }
    }
    // ---- kc2 boundary: restage A halo (all waves' reads done at last barrier)
    if (kc2 < 3) {
      STAGE_A((size_t)(kc2 + 1) * 8 * PLANE);
      asm volatile("s_waitcnt vmcnt(0)" ::: "memory");
      __builtin_amdgcn_s_barrier();
    }
  }

  // ---- epilogue (R7-verbatim): D row = pixel (quad*4+reg), col = o (lane&15)
  int pixbase = m0 & 4095;
  int quad = lane >> 4;
  int col = lane & 15;
#pragma unroll
  for (int mi = 0; mi < 8; mi++) {
    int pm = pixbase + wm * 128 + mi * 16 + quad * 4;
#pragma unroll
    for (int ni = 0; ni < 4; ni++) {
      int on = wn * 64 + ni * 16 + col;
      float* op = out + ((size_t)(b * COUT + on) << 12) + pm;
      *(f32x4*)op = acc[mi][ni];
    }
  }
}

extern "C" void kernel_launch(void* const* d_in, const int* in_sizes, int n_in,
                              void* d_out, int out_size, void* d_ws, size_t ws_size,
                              hipStream_t stream) {
  const float* x = (const float*)d_in[0];
  const float* y = (const float*)d_in[1];
  const float* w0 = (const float*)d_in[2];
  const float* b0 = (const float*)d_in[3];
  const float* w1 = (const float*)d_in[4];
  const float* b1 = (const float*)d_in[5];
  const float* w2 = (const float*)d_in[6];
  const float* b2 = (const float*)d_in[7];
  const float* cw = (const float*)d_in[8];
  float* out = (float*)d_out;

  // xpad FIRST so the A-halo's tail over-read lands in wt, inside ws.
  char* ws = (char*)d_ws;
  unsigned short* xpad = (unsigned short*)ws;                   // 35,684,352 B
  unsigned short* wt = (unsigned short*)(ws + 35684352);        // 2,359,296 B
  float* t0 = (float*)(ws + 35684352 + 2359296);                // 16 KiB
  float* t1 = (float*)(ws + 35684352 + 2359296 + 16384);        // 16 KiB

  mlp_layer<DCAT><<<BATCH * CIN / 4, 256, 0, stream>>>(y, w0, b0, t0);
  mlp_layer<CIN><<<BATCH * CIN / 4, 256, 0, stream>>>(t0, w1, b1, t1);
  prep_all<<<1024 + 576, 256, 0, stream>>>(t1, w2, b2, x, cw, xpad, wt);
  gemm_conv<<<BATCH * HH * WW / 256, 512, 0, stream>>>(xpad, wt, out);
}

// Round 12
// 204.906 us; speedup vs baseline: 1.1140x; 1.1140x over previous
//
#include <hip/hip_runtime.h>

typedef short bf16x8 __attribute__((ext_vector_type(8)));
typedef float f32x4 __attribute__((ext_vector_type(4)));
typedef unsigned short ushort8 __attribute__((ext_vector_type(8)));
typedef unsigned short ushort4v __attribute__((ext_vector_type(4)));

#define BATCH 16
#define DCAT 512
#define CIN 256
#define COUT 256
#define HH 64
#define WW 64
#define HP 66
#define WP 66
#define PLANE (HP * WP * 8)  // shorts per c8-plane
#define ABH 33792            // A halo: 264 entries (4 rows x 66 cols) * 128B
#define BB 16384             // one B buffer: 128 o x 64 ch x 2B

__device__ __forceinline__ unsigned short f2bf(float f) {
  unsigned int u = __float_as_uint(f);
  unsigned int r = (u + 0x7fffu + ((u >> 16) & 1u)) >> 16;
  return (unsigned short)r;
}

// ---------------- MLP layer: one wave per output element (b,c).
template <int IN_DIM>
__global__ void __launch_bounds__(256) mlp_layer(const float* __restrict__ in,
                                                 const float* __restrict__ w,
                                                 const float* __restrict__ bias,
                                                 float* __restrict__ out) {
  int wid = threadIdx.x >> 6, lane = threadIdx.x & 63;
  int oidx = blockIdx.x * 4 + wid;  // (b<<8)|c
  int b = oidx >> 8, c = oidx & 255;
  const float* wr = w + (size_t)c * IN_DIM;
  const float* ir = in + (size_t)b * IN_DIM;
  float sum = 0.f;
#pragma unroll
  for (int d0 = 0; d0 < IN_DIM; d0 += 256) {
    f32x4 wv = *(const f32x4*)(wr + d0 + lane * 4);
    f32x4 iv = *(const f32x4*)(ir + d0 + lane * 4);
    sum += wv[0] * iv[0] + wv[1] * iv[1] + wv[2] * iv[2] + wv[3] * iv[3];
  }
#pragma unroll
  for (int off = 32; off; off >>= 1) sum += __shfl_xor(sum, off, 64);
  if (lane == 0) {
    float a = sum + bias[c];
    out[oidx] = a >= 0.f ? a : 0.01f * a;
  }
}

// ---------------- consolidated prep (tap-major wt): R0-verbatim.
__global__ void __launch_bounds__(256) prep_all(const float* __restrict__ t1,
                                                const float* __restrict__ w2,
                                                const float* __restrict__ b2,
                                                const float* __restrict__ x,
                                                const float* __restrict__ cw,
                                                unsigned short* __restrict__ xpad,
                                                unsigned short* __restrict__ wt) {
  int blk = blockIdx.x;
  int tid = threadIdx.x;

  if (blk >= 1024) {  // ---- prep_w part
    int idx = (blk - 1024) * 256 + tid;  // 9*256*64 = 147456 threads
    int t = idx / 16384;
    int r = idx - t * 16384;  // o*64 + i4
    int o = r >> 6, i4 = r & 63;
    ushort4v v;
#pragma unroll
    for (int j = 0; j < 4; j++) v[j] = f2bf(cw[(o * 256 + i4 * 4 + j) * 9 + t]);
    *(ushort4v*)(wt + ((size_t)(t * COUT + o)) * CIN + i4 * 4) = v;
    return;
  }

  // ---- prep_x part: blk = (b<<6) | (c8<<1) | h
  int h = blk & 1, c8 = (blk >> 1) & 31, b = blk >> 6;
  int wid = tid >> 6, lane = tid & 63;

  float tv = t1[b * CIN + tid];
  float pj[8];
#pragma unroll
  for (int j = 0; j < 8; j++) pj[j] = w2[(size_t)(c8 * 8 + j) * CIN + tid] * tv;

  const float* xb = x + ((size_t)(b * CIN + c8 * 8)) * (HH * WW);
  int gg0 = h * 512 + tid;
  int gg1 = gg0 + 256;
  int hh0 = (gg0 >> 4) + 1, w00 = (gg0 & 15) * 4 + 1;
  int hh1 = (gg1 >> 4) + 1, w01 = (gg1 & 15) * 4 + 1;
  int base0 = (hh0 - 1) * WW + (w00 - 1);
  int base1 = (hh1 - 1) * WW + (w01 - 1);
  f32x4 v0[8], v1[8];
#pragma unroll
  for (int j = 0; j < 8; j++) v0[j] = *(const f32x4*)(xb + j * (HH * WW) + base0);
#pragma unroll
  for (int j = 0; j < 8; j++) v1[j] = *(const f32x4*)(xb + j * (HH * WW) + base1);

#pragma unroll
  for (int off = 32; off; off >>= 1)
#pragma unroll
    for (int j = 0; j < 8; j++) pj[j] += __shfl_xor(pj[j], off, 64);
  __shared__ float red[4][8];
  __shared__ float sv_sh[8];
  if (lane == 0)
#pragma unroll
    for (int j = 0; j < 8; j++) red[wid][j] = pj[j];
  __syncthreads();
  if (tid < 8) {
    float a = red[0][tid] + red[1][tid] + red[2][tid] + red[3][tid] + b2[c8 * 8 + tid];
    sv_sh[tid] = a >= 0.f ? a : 0.01f * a;
  }
  __syncthreads();
  float sv[8];
#pragma unroll
  for (int j = 0; j < 8; j++) sv[j] = sv_sh[j];

  unsigned short* xp = xpad + ((size_t)(b * 32 + c8)) * PLANE;

  if (tid < 130) {
    int i = h * 130 + tid;
    int bh, bw;
    if (i < 66) { bh = 0; bw = i; }
    else if (i < 132) { bh = 65; bw = i - 66; }
    else if (i < 196) { bh = i - 132 + 1; bw = 0; }
    else { bh = i - 196 + 1; bw = 65; }
    ushort8 z = {0, 0, 0, 0, 0, 0, 0, 0};
    *(ushort8*)(xp + (bh * WP + bw) * 8) = z;
  }

  unsigned short* op0 = xp + (hh0 * WP + w00) * 8;
  unsigned short* op1 = xp + (hh1 * WP + w01) * 8;
#pragma unroll
  for (int t2 = 0; t2 < 4; t2++) {
    ushort8 o;
#pragma unroll
    for (int j = 0; j < 8; j++) o[j] = f2bf(v0[j][t2] * sv[j]);
    *(ushort8*)(op0 + t2 * 8) = o;
  }
#pragma unroll
  for (int t2 = 0; t2 < 4; t2++) {
    ushort8 o;
#pragma unroll
    for (int j = 0; j < 8; j++) o[j] = f2bf(v1[j][t2] * sv[j]);
    *(ushort8*)(op1 + t2 * 8) = o;
  }
}

// ---------------- implicit-GEMM conv R12: tap-reuse at 2 blocks/CU.
// Block = 128px x 128o, 4 waves (2x2) of 64x64, acc[4][4] (64 VGPR).
// A halo (4 rows x 66 cols x 64ch, 33KB) staged once per kc2; B (16KB)
// double-buffered with R7's full-tap-cover staging; 1 barrier/tap.
// LDS 65KB -> TWO independent blocks per CU: their barrier stalls and
// ds_read floods anti-phase against each other's MFMA clusters (the R0
// cross-block overlap), on top of R7's minimal LDS traffic.
__device__ __forceinline__ void gl2lds16(const void* g, void* l) {
  __builtin_amdgcn_global_load_lds((const __attribute__((address_space(1))) void*)g,
                                   (__attribute__((address_space(3))) void*)l, 16, 0, 0);
}

__global__ void __launch_bounds__(256, 2) gemm_conv(const unsigned short* __restrict__ xpad,
                                                    const unsigned short* __restrict__ wt,
                                                    float* __restrict__ out) {
  // LDS: A halo [0, 33792), B buf0 [33792, +16K), B buf1 [50176, +16K)
  __shared__ __align__(16) char lds[ABH + 2 * BB];
  int tid = threadIdx.x;
  int wid = tid >> 6, lane = tid & 63;
  int bid = blockIdx.x;
  // XCD swizzle: 1024 blocks, 128 contiguous wgids per XCD; wgid pairs
  // (2 o-halves of one px-tile) stay on the same XCD for A-halo L2 reuse.
  int wgid = (bid & 7) * 128 + (bid >> 3);
  int m_t = wgid >> 1;               // px-tile 0..511 (2 image rows each)
  int oh = wgid & 1;                 // o-half: o in [oh*128, oh*128+128)
  int m0 = m_t << 7;
  int b = m0 >> 12;
  int h0 = (m0 >> 6) & 63;           // tile covers image rows h0, h0+1 (h0 even)
  int wm = wid & 1, wn = wid >> 1;   // 2x2 wave grid, wave tile 64px x 64o

  f32x4 acc[4][4];
#pragma unroll
  for (int mi = 0; mi < 4; mi++)
#pragma unroll
    for (int ni = 0; ni < 4; ni++) acc[mi][ni] = (f32x4){0.f, 0.f, 0.f, 0.f};

  // ---- stager lane invariants. Chunk-linear staging: load c covers entry
  // e = c>>3, slot cs = c&7 holding global chunk gs = cs ^ (e&7); both A
  // (entries = halo cells) and B (entries = o-rows) use stride-66/row and
  // row-major-128B layouts with e&7 ≡ (tid>>3)&7 per round (rounds are
  // multiples of 256 ≡ 0 mod 8) -> gs is round-independent.
  int gsw = (tid & 7) ^ ((tid >> 3) & 7);
  const unsigned short* aSrc[9];
#pragma unroll
  for (int i = 0; i < 9; i++) {
    int e = i * 32 + (tid >> 3);     // i=8 valid only for tid<64 (guarded at use)
    int rh = e / 66, wc = e - rh * 66;
    aSrc[i] = xpad + ((size_t)((b * 32 + gsw) * HP + (h0 + rh))) * (WP * 8) + wc * 8;
  }
  const unsigned short* bS = wt + (size_t)(oh * 128 + (tid >> 3)) * CIN + gsw * 8;

  // ---- reader invariants
  int qa = lane >> 4;
  int l15 = lane & 15;
  int orow = wn * 64 + l15;
  int offB0 = orow * 128 + ((qa ^ (l15 & 7)) * 16);
  int offB1 = orow * 128 + (((qa + 4) ^ (l15 & 7)) * 16);

#define STAGE_A(KC2)                                                     \
  do {                                                                   \
    size_t ko_ = (size_t)(KC2) * 8 * PLANE;                              \
    _Pragma("unroll")                                                    \
    for (int i = 0; i < 8; i++)                                          \
      gl2lds16(aSrc[i] + ko_, lds + i * 4096 + wid * 1024);              \
    if (wid == 0) gl2lds16(aSrc[8] + ko_, lds + 32768);                  \
  } while (0)

#define STAGE_B(BUF, TAP, KC2)                                           \
  do {                                                                   \
    const unsigned short* s_ = bS + (size_t)(TAP) * (COUT * CIN) + (KC2) * 64; \
    char* d_ = lds + ABH + (BUF) * BB + wid * 1024;                      \
    _Pragma("unroll")                                                    \
    for (int q = 0; q < 4; q++)                                          \
      gl2lds16(s_ + q * 32 * CIN, d_ + q * 4096);                        \
  } while (0)

  // ---- prologue: A halo kc2=0 + B(tap0,kc2=0) into buf 0
  STAGE_A(0);
  STAGE_B(0, 0, 0);
  asm volatile("s_waitcnt vmcnt(0)" ::: "memory");
  __builtin_amdgcn_s_barrier();

  int cur = 0;
  for (int kc2 = 0; kc2 < 4; kc2++) {
    for (int kh = 0; kh < 3; kh++) {
      for (int kw = 0; kw < 3; kw++) {
        int tap = kh * 3 + kw;
        // stage next B (full tap of cover before the tap-end barrier drain)
        if (tap < 8) {
          STAGE_B(cur ^ 1, tap + 1, kc2);
        } else if (kc2 < 3) {
          STAGE_B(cur ^ 1, 0, kc2 + 1);
        }

        // A window: wave wm = image row h0+wm; entry e = (wm+kh)*66 + col+kw
        int e0 = (wm + kh) * 66 + l15 + kw;
        int s0 = e0 & 7;
        int a00 = e0 * 128 + ((qa ^ s0) * 16);
        int a10 = e0 * 128 + (((qa + 4) ^ s0) * 16);
        const char* Bb = lds + ABH + cur * BB;

        bf16x8 av[4], aw[4], bv[4], bw[4];
#pragma unroll
        for (int mi = 0; mi < 4; mi++) {
          av[mi] = *(const bf16x8*)(lds + a00 + mi * 2048);
          aw[mi] = *(const bf16x8*)(lds + a10 + mi * 2048);
        }
#pragma unroll
        for (int ni = 0; ni < 4; ni++) {
          bv[ni] = *(const bf16x8*)(Bb + offB0 + ni * 2048);
          bw[ni] = *(const bf16x8*)(Bb + offB1 + ni * 2048);
        }

        __builtin_amdgcn_s_setprio(1);
#pragma unroll
        for (int mi = 0; mi < 4; mi++)
#pragma unroll
          for (int ni = 0; ni < 4; ni++)
            acc[mi][ni] = __builtin_amdgcn_mfma_f32_16x16x32_bf16(av[mi], bv[ni],
                                                                  acc[mi][ni], 0, 0, 0);
#pragma unroll
        for (int mi = 0; mi < 4; mi++)
#pragma unroll
          for (int ni = 0; ni < 4; ni++)
            acc[mi][ni] = __builtin_amdgcn_mfma_f32_16x16x32_bf16(aw[mi], bw[ni],
                                                                  acc[mi][ni], 0, 0, 0);
        __builtin_amdgcn_s_setprio(0);

        __syncthreads();  // drains vmcnt(0): next-B landed under this tap's cover
        cur ^= 1;
      }
    }
    // ---- kc2 boundary: restage A halo (all reads done at last tap barrier)
    if (kc2 < 3) {
      STAGE_A(kc2 + 1);
      asm volatile("s_waitcnt vmcnt(0)" ::: "memory");
      __builtin_amdgcn_s_barrier();
    }
  }

  // ---- epilogue: D row = px (quad*4+reg within 16-block), col = o (lane&15)
  int pixbase = m0 & 4095;  // = h0*64
  int quad = lane >> 4;
  int col = lane & 15;
#pragma unroll
  for (int mi = 0; mi < 4; mi++) {
    int pm = pixbase + wm * 64 + mi * 16 + quad * 4;
#pragma unroll
    for (int ni = 0; ni < 4; ni++) {
      int on = oh * 128 + wn * 64 + ni * 16 + col;
      float* op = out + ((size_t)(b * COUT + on) << 12) + pm;
      *(f32x4*)op = acc[mi][ni];
    }
  }
}

extern "C" void kernel_launch(void* const* d_in, const int* in_sizes, int n_in,
                              void* d_out, int out_size, void* d_ws, size_t ws_size,
                              hipStream_t stream) {
  const float* x = (const float*)d_in[0];
  const float* y = (const float*)d_in[1];
  const float* w0 = (const float*)d_in[2];
  const float* b0 = (const float*)d_in[3];
  const float* w1 = (const float*)d_in[4];
  const float* b1 = (const float*)d_in[5];
  const float* w2 = (const float*)d_in[6];
  const float* b2 = (const float*)d_in[7];
  const float* cw = (const float*)d_in[8];
  float* out = (float*)d_out;

  // xpad FIRST so the A-halo's tail over-read lands in wt, inside ws.
  char* ws = (char*)d_ws;
  unsigned short* xpad = (unsigned short*)ws;                   // 35,684,352 B
  unsigned short* wt = (unsigned short*)(ws + 35684352);        // 2,359,296 B
  float* t0 = (float*)(ws + 35684352 + 2359296);                // 16 KiB
  float* t1 = (float*)(ws + 35684352 + 2359296 + 16384);        // 16 KiB

  mlp_layer<DCAT><<<BATCH * CIN / 4, 256, 0, stream>>>(y, w0, b0, t0);
  mlp_layer<CIN><<<BATCH * CIN / 4, 256, 0, stream>>>(t0, w1, b1, t1);
  prep_all<<<1024 + 576, 256, 0, stream>>>(t1, w2, b2, x, cw, xpad, wt);
  gemm_conv<<<BATCH * HH * WW / 128 * 2, 256, 0, stream>>>(xpad, wt, out);
}